// Round 2
// baseline (1502.789 us; speedup 1.0000x reference)
//
#include <hip/hip_runtime.h>

// x[2048,64,2] -> MLP(2->16 relu ->16) -> 8x LSTM(H=64) -> MLP(64->32 relu ->4)
// fp32 in/out. LSTM via split-bf16 MFMA (3-term, ~fp32 accuracy).
//
// Round 7: layer-wavefront persistent LSTM.
//   ONE kernel, grid 256 x 512 threads: block (l = bid>>5, g = bid&31) runs layer l
//   for batch rows [64g, 64g+64) over all t, pipelined across layers via a global
//   ring buffer (8 slots) + agent-scope acquire/release flags.
//   M=64: all 16 MFMA rows real (total MFMA work halved vs M=8).
//   Waves: 8 = (mw 0..1: rows 32mw..+32) x (nw 0..3: j in [16nw,16nw+16)).
//   Gate-per-tile weight permutation: tile gt holds gate gt (i,f,g,o) for the
//   wave's 16 j's  =>  each lane's D fragments hold ALL 4 gates for its 4 rows
//   => phase C fully register-local (no gate LDS, no gate barrier).
//   h handoff: packed (hi16|lo16) u32 ring slots; consumer unpacks straight into
//   its bf16 panel (bit-identical to fp32 split path).
//   Panel parity double-buffered, LDP=136. 3 barriers/step (flag, stage, end).

#define BATCH 2048
#define TT 64
#define HH 64
#define LDP 136   // panel row stride in shorts
#define GRP 32    // batch groups (2048/64)
#define RING 8    // ring slots (timesteps of slack)

typedef short bf16x8 __attribute__((ext_vector_type(8)));
typedef float f32x4 __attribute__((ext_vector_type(4)));
typedef unsigned short u16x4 __attribute__((ext_vector_type(4)));

__device__ __forceinline__ float sigmoid_fast(float x) {
    return __builtin_amdgcn_rcpf(1.f + __expf(-x));
}
__device__ __forceinline__ float tanh_fast(float x) {
    float e = __expf(-2.f * x);
    e = fminf(e, 1e30f);          // keep 1+e finite so rcp>0: tanh(-big) -> -1, not NaN
    return (1.f - e) * __builtin_amdgcn_rcpf(1.f + e);
}
__device__ __forceinline__ void split2(float x, unsigned short& hi, unsigned short& lo) {
    const unsigned u = __float_as_uint(x);
    hi = (unsigned short)(u >> 16);
    const float r = x - __uint_as_float(u & 0xFFFF0000u);  // exact
    lo = (unsigned short)(__float_as_uint(r) >> 16);
}

// ---------------- input MLP: 2 -> 16 relu -> 16 ----------------
__global__ __launch_bounds__(256)
void mlp_in_kernel(const float* __restrict__ x,
                   const float* __restrict__ w1, const float* __restrict__ b1,
                   const float* __restrict__ w2, const float* __restrict__ b2,
                   float* __restrict__ out) {
    const int gid = blockIdx.x * 256 + threadIdx.x;
    const float x0 = x[gid * 2 + 0];
    const float x1 = x[gid * 2 + 1];
    float hid[16];
#pragma unroll
    for (int j = 0; j < 16; ++j) {
        float v = fmaf(x1, w1[j * 2 + 1], fmaf(x0, w1[j * 2 + 0], b1[j]));
        hid[j] = fmaxf(0.f, v);
    }
    float o[16];
#pragma unroll
    for (int oo = 0; oo < 16; ++oo) {
        float acc = b2[oo];
#pragma unroll
        for (int j = 0; j < 16; ++j) acc = fmaf(hid[j], w2[oo * 16 + j], acc);
        o[oo] = acc;
    }
    float4* op = (float4*)(out + gid * 16);
#pragma unroll
    for (int q = 0; q < 4; ++q) {
        float4 v;
        v.x = o[q * 4 + 0]; v.y = o[q * 4 + 1]; v.z = o[q * 4 + 2]; v.w = o[q * 4 + 3];
        op[q] = v;
    }
}

// ---------------- wavefront LSTM: all 8 layers, one kernel ----------------
__global__ __launch_bounds__(512, 2)
void lstm_wavefront(const float* __restrict__ xmlp,
                    const float* __restrict__ w_ih0, const float* __restrict__ w_hh0,
                    const float* __restrict__ b_ih0, const float* __restrict__ b_hh0,
                    const float* __restrict__ w_ih, const float* __restrict__ w_hh,
                    const float* __restrict__ b_ih, const float* __restrict__ b_hh,
                    unsigned* __restrict__ hring,   // [7][GRP][RING][64][64] u32 (hi|lo)
                    float* __restrict__ houtf,      // [B][T][64] final-layer h
                    int* __restrict__ prog,         // [8][GRP]
                    int* __restrict__ cons)         // [8][GRP]
{
    const int bid = blockIdx.x;
    const int l = bid >> 5, g = bid & (GRP - 1);
    const int tid = threadIdx.x;
    const int wv = tid >> 6, lane = tid & 63, l16 = lane & 15, quad = lane >> 4;
    const int mw = wv >> 2, nw = wv & 3;

    const int I    = (l == 0) ? 16 : 64;
    const int IPAD = (l == 0) ? 32 : 64;
    const int KT   = (l == 0) ? 3 : 4;
    const float* wih = (l == 0) ? w_ih0 : (w_ih + (size_t)(l - 1) * 256 * 64);
    const float* whh = (l == 0) ? w_hh0 : (w_hh + (size_t)(l - 1) * 256 * 64);
    const float* bi  = (l == 0) ? b_ih0 : (b_ih + (l - 1) * 256);
    const float* bh  = (l == 0) ? b_hh0 : (b_hh + (l - 1) * 256);

    __shared__ unsigned short ph[2][64 * LDP];  // parity panels, hi plane
    __shared__ unsigned short pl[2][64 * LDP];  // lo plane

    for (int e = tid; e < 64 * LDP; e += 512) {
        ph[0][e] = 0; pl[0][e] = 0; ph[1][e] = 0; pl[1][e] = 0;
    }

    // --- weight B-fragments, gate-per-tile permutation ---
    // tile gt holds gate gt; col l16 -> j = 16*nw + l16; weight row n = gt*64 + j.
    bf16x8 bhi[4][4], blo[4][4];  // [kt][gt]
    float bsum[4];
#pragma unroll
    for (int gt = 0; gt < 4; ++gt) {
        const int n = gt * 64 + 16 * nw + l16;
        bsum[gt] = bi[n] + bh[n];
#pragma unroll
        for (int kt = 0; kt < 4; ++kt) {
            bf16x8 vh = {0, 0, 0, 0, 0, 0, 0, 0};
            bf16x8 vl = {0, 0, 0, 0, 0, 0, 0, 0};
            if (kt < KT) {
#pragma unroll
                for (int j = 0; j < 8; ++j) {
                    const int k = kt * 32 + quad * 8 + j;
                    float w = 0.f;
                    if (k < I) w = wih[n * I + k];
                    else if (k >= IPAD) w = whh[n * 64 + (k - IPAD)];
                    unsigned short h_, l_;
                    split2(w, h_, l_);
                    vh[j] = (short)h_;
                    vl[j] = (short)l_;
                }
            }
            bhi[kt][gt] = vh;
            blo[kt][gt] = vl;
        }
    }

    // c-state: lane owns rows {mt*16 + quad*4 + rr} x col j = 16nw+l16, mt in {2mw, 2mw+1}
    float cst[2][4];
#pragma unroll
    for (int q = 0; q < 4; ++q) { cst[0][q] = 0.f; cst[1][q] = 0.f; }

    int* myprog = prog + l * GRP + g;
    int* upprog = prog + (l > 0 ? (l - 1) : 0) * GRP + g;
    int* mycons = cons + l * GRP + g;
    int* dncons = cons + (l < 7 ? (l + 1) : 7) * GRP + g;
    const unsigned* hr_src = hring + ((size_t)((l > 0 ? l - 1 : 0) * GRP + g)) * (RING * 4096);
    unsigned* hr_dst = hring + ((size_t)((l < 7 ? l : 6) * GRP + g)) * (RING * 4096);

    const int jg = 16 * nw + l16;

    __syncthreads();  // panel zero-init done

    for (int t = 0; t < TT; ++t) {
        const int pb = t & 1;

        // ---- flag waits (thread 0 only) ----
        if (tid == 0) {
            if (l > 0) {
                while (__hip_atomic_load(upprog, __ATOMIC_ACQUIRE, __HIP_MEMORY_SCOPE_AGENT) < t + 1)
                    __builtin_amdgcn_s_sleep(1);
            }
            if (l < 7 && t >= RING) {
                while (__hip_atomic_load(dncons, __ATOMIC_ACQUIRE, __HIP_MEMORY_SCOPE_AGENT) < t - (RING - 1))
                    __builtin_amdgcn_s_sleep(1);
            }
        }
        __syncthreads();  // S1: flag satisfied, caches invalidated

        // ---- stage x(t) into panel[pb] x-region ----
        if (l == 0) {
            if (tid < 256) {
                const int r = tid >> 2, q = tid & 3;
                const float4 v = *(const float4*)&xmlp[(((size_t)(g * 64 + r)) * TT + t) * 16 + q * 4];
                unsigned short h0, h1, h2, h3, e0, e1, e2, e3;
                split2(v.x, h0, e0); split2(v.y, h1, e1);
                split2(v.z, h2, e2); split2(v.w, h3, e3);
                u16x4 hv = {h0, h1, h2, h3};
                u16x4 lv = {e0, e1, e2, e3};
                *(u16x4*)&ph[pb][r * LDP + q * 4] = hv;
                *(u16x4*)&pl[pb][r * LDP + q * 4] = lv;
            }
        } else {
            const int r = tid >> 3, q = tid & 7;
            const unsigned* s = hr_src + (size_t)(t & (RING - 1)) * 4096 + r * 64 + q * 8;
            const uint4 v0 = *(const uint4*)s;
            const uint4 v1 = *(const uint4*)(s + 4);
            bf16x8 hv, lv;
            hv[0] = (short)(v0.x >> 16); lv[0] = (short)(v0.x & 0xffffu);
            hv[1] = (short)(v0.y >> 16); lv[1] = (short)(v0.y & 0xffffu);
            hv[2] = (short)(v0.z >> 16); lv[2] = (short)(v0.z & 0xffffu);
            hv[3] = (short)(v0.w >> 16); lv[3] = (short)(v0.w & 0xffffu);
            hv[4] = (short)(v1.x >> 16); lv[4] = (short)(v1.x & 0xffffu);
            hv[5] = (short)(v1.y >> 16); lv[5] = (short)(v1.y & 0xffffu);
            hv[6] = (short)(v1.z >> 16); lv[6] = (short)(v1.z & 0xffffu);
            hv[7] = (short)(v1.w >> 16); lv[7] = (short)(v1.w & 0xffffu);
            *(bf16x8*)&ph[pb][r * LDP + q * 8] = hv;
            *(bf16x8*)&pl[pb][r * LDP + q * 8] = lv;
        }
        __syncthreads();  // S2: panel[pb] complete (x staged; h written last step)
        if (tid == 0 && l > 0)
            __hip_atomic_store(mycons, t + 1, __ATOMIC_RELEASE, __HIP_MEMORY_SCOPE_AGENT);

        const unsigned short* php = ph[pb];
        const unsigned short* plp = pl[pb];
        unsigned short* phn = ph[pb ^ 1];
        unsigned short* pln = pl[pb ^ 1];

        // ---- per-chunk: MFMA -> register-local phase C ----
#pragma unroll
        for (int ch = 0; ch < 2; ++ch) {
            const int mt = mw * 2 + ch;
            f32x4 a0[4], a1[4], a2[4];
#pragma unroll
            for (int gt = 0; gt < 4; ++gt) {
                a0[gt][0] = bsum[gt]; a0[gt][1] = bsum[gt];
                a0[gt][2] = bsum[gt]; a0[gt][3] = bsum[gt];
                a1[gt] = (f32x4){0.f, 0.f, 0.f, 0.f};
                a2[gt] = (f32x4){0.f, 0.f, 0.f, 0.f};
            }
#pragma unroll
            for (int kt = 0; kt < 4; ++kt) {
                if (kt < KT) {
                    const int aoff = (mt * 16 + l16) * LDP + kt * 32 + quad * 8;
                    const bf16x8 ahi = *(const bf16x8*)&php[aoff];
                    const bf16x8 alo = *(const bf16x8*)&plp[aoff];
#pragma unroll
                    for (int gt = 0; gt < 4; ++gt) {
                        a0[gt] = __builtin_amdgcn_mfma_f32_16x16x32_bf16(ahi, bhi[kt][gt], a0[gt], 0, 0, 0);
                        a1[gt] = __builtin_amdgcn_mfma_f32_16x16x32_bf16(alo, bhi[kt][gt], a1[gt], 0, 0, 0);
                        a2[gt] = __builtin_amdgcn_mfma_f32_16x16x32_bf16(ahi, blo[kt][gt], a2[gt], 0, 0, 0);
                    }
                }
            }
            // phase C: lane holds ALL 4 gates for rows quad*4+rr of this mt
#pragma unroll
            for (int rr = 0; rr < 4; ++rr) {
                const float gi = (a0[0][rr] + a1[0][rr]) + a2[0][rr];
                const float gf = (a0[1][rr] + a1[1][rr]) + a2[1][rr];
                const float gg = (a0[2][rr] + a1[2][rr]) + a2[2][rr];
                const float go = (a0[3][rr] + a1[3][rr]) + a2[3][rr];
                const float iv = sigmoid_fast(gi), fv = sigmoid_fast(gf);
                const float gv = tanh_fast(gg), ov = sigmoid_fast(go);
                const float cn = fv * cst[ch][rr] + iv * gv;
                cst[ch][rr] = cn;
                const float h = ov * tanh_fast(cn);
                const int R = mt * 16 + quad * 4 + rr;
                unsigned short h_, l_;
                split2(h, h_, l_);
                phn[R * LDP + IPAD + jg] = h_;
                pln[R * LDP + IPAD + jg] = l_;
                if (l < 7) {
                    hr_dst[(size_t)(t & (RING - 1)) * 4096 + R * 64 + jg] =
                        ((unsigned)h_ << 16) | (unsigned)l_;
                } else {
                    houtf[(((size_t)(g * 64 + R)) * TT + t) * HH + jg] = h;
                }
            }
        }
        __syncthreads();  // S3: h(t) in panel[pb^1]; vmcnt drained (ring writes done)
        if (tid == 0 && l < 7)
            __hip_atomic_store(myprog, t + 1, __ATOMIC_RELEASE, __HIP_MEMORY_SCOPE_AGENT);
    }
}

// ---------------- output MLP: 64 -> 32 relu -> 4 ----------------
__global__ __launch_bounds__(256)
void mlp_out_kernel(const float* __restrict__ hin,
                    const float* __restrict__ wo1, const float* __restrict__ bo1,
                    const float* __restrict__ wo2, const float* __restrict__ bo2,
                    float* __restrict__ out) {
    __shared__ __align__(16) float wo1_s[32 * 64];
    __shared__ float bo1_s[32];
    __shared__ float wo2_s[4 * 32];
    __shared__ float bo2_s[4];
    const int tid = threadIdx.x;
    for (int e = tid; e < 32 * 64; e += 256) wo1_s[e] = wo1[e];
    if (tid < 32) bo1_s[tid] = bo1[tid];
    if (tid < 128) wo2_s[tid] = wo2[tid];
    if (tid < 4) bo2_s[tid] = bo2[tid];
    __syncthreads();

    const int gid = blockIdx.x * 256 + tid;
    const float4* hv = (const float4*)(hin + gid * 64);
    float4 h[16];
#pragma unroll
    for (int q = 0; q < 16; ++q) h[q] = hv[q];

    float m1[32];
#pragma unroll
    for (int o = 0; o < 32; ++o) {
        float acc = bo1_s[o];
        const float4* wrow = (const float4*)(wo1_s + o * 64);
#pragma unroll
        for (int q = 0; q < 16; ++q) {
            const float4 w = wrow[q];
            acc = fmaf(h[q].x, w.x, acc);
            acc = fmaf(h[q].y, w.y, acc);
            acc = fmaf(h[q].z, w.z, acc);
            acc = fmaf(h[q].w, w.w, acc);
        }
        m1[o] = fmaxf(0.f, acc);
    }
    float r[4];
#pragma unroll
    for (int q = 0; q < 4; ++q) {
        float acc = bo2_s[q];
#pragma unroll
        for (int o = 0; o < 32; ++o) acc = fmaf(m1[o], wo2_s[q * 32 + o], acc);
        r[q] = acc;
    }
    float4 res;
    res.x = r[0]; res.y = r[1]; res.z = r[2]; res.w = r[3];
    ((float4*)out)[gid] = res;
}

extern "C" void kernel_launch(void* const* d_in, const int* in_sizes, int n_in,
                              void* d_out, int out_size, void* d_ws, size_t ws_size,
                              hipStream_t stream) {
    const float* x     = (const float*)d_in[0];
    const float* w1    = (const float*)d_in[1];
    const float* b1    = (const float*)d_in[2];
    const float* w2    = (const float*)d_in[3];
    const float* b2    = (const float*)d_in[4];
    const float* w_ih0 = (const float*)d_in[5];
    const float* w_hh0 = (const float*)d_in[6];
    const float* b_ih0 = (const float*)d_in[7];
    const float* b_hh0 = (const float*)d_in[8];
    const float* w_ih  = (const float*)d_in[9];
    const float* w_hh  = (const float*)d_in[10];
    const float* b_ih  = (const float*)d_in[11];
    const float* b_hh  = (const float*)d_in[12];
    const float* wo1   = (const float*)d_in[13];
    const float* bo1   = (const float*)d_in[14];
    const float* wo2   = (const float*)d_in[15];
    const float* bo2   = (const float*)d_in[16];

    // workspace layout (fp32 units unless noted):
    //   buf_mlp: B*T*16        = 2,097,152 f  (8 MB)
    //   bufH   : B*T*64        = 8,388,608 f  (32 MB)   final-layer h
    //   hring  : 7*32*8*64*64  = 7,340,032 u32 (28 MB)
    //   flags  : prog[256] + cons[256] ints
    float* buf_mlp = (float*)d_ws;
    float* bufH = buf_mlp + (size_t)BATCH * TT * 16;
    unsigned* hring = (unsigned*)(bufH + (size_t)BATCH * TT * 64);
    int* flags = (int*)(hring + (size_t)7 * GRP * RING * 64 * 64);
    int* prog = flags;
    int* cons = flags + 8 * GRP;

    const int nbt_blocks = (BATCH * TT) / 256;  // 512

    // reset sync flags every launch (graph replays!)
    hipMemsetAsync(flags, 0, 2 * 8 * GRP * sizeof(int), stream);

    mlp_in_kernel<<<nbt_blocks, 256, 0, stream>>>(x, w1, b1, w2, b2, buf_mlp);

    lstm_wavefront<<<8 * GRP, 512, 0, stream>>>(
        buf_mlp, w_ih0, w_hh0, b_ih0, b_hh0,
        w_ih, w_hh, b_ih, b_hh,
        hring, bufH, prog, cons);

    mlp_out_kernel<<<nbt_blocks, 256, 0, stream>>>(bufH, wo1, bo1, wo2, bo2, (float*)d_out);
}

// Round 3
// 571.073 us; speedup vs baseline: 2.6315x; 2.6315x over previous
//
#include <hip/hip_runtime.h>

// x[2048,64,2] -> MLP(2->16 relu ->16) -> 8x LSTM(H=64) -> MLP(64->32 relu ->4)
// fp32 in/out. LSTM via split-bf16 MFMA (3-term, ~fp32 accuracy).
//
// Round 8: intra-block layer pairing (NO cross-block sync).
//   4 dispatches, each fuses layers (2p, 2p+1). grid 256 x 512 threads, M=8.
//   Waves 0-3: layer A at step t. Waves 4-7: layer B at step t-1 (1-step skew).
//   Each wave owns 4 gate-tiles (i,f,g,o) for 16 hidden units -> phase C fully
//   register-local (no gate LDS). Weights in registers (128 VGPR/wave).
//   A's h -> B's input panel via LDS (double-buffered); B's h -> packed u32
//   (hi|lo) global buffer consumed by the next dispatch's A (3-step-margin
//   in-place overwrite => ONE shared buffer). 1 barrier/step, 65 steps.
//   Split-term summation order identical to the verified R1 kernel.

#define BATCH 2048
#define TT 64
#define HH 64
#define LDP 136   // panel row stride in shorts

typedef short bf16x8 __attribute__((ext_vector_type(8)));
typedef float f32x4 __attribute__((ext_vector_type(4)));

__device__ __forceinline__ float sigmoid_fast(float x) {
    return __builtin_amdgcn_rcpf(1.f + __expf(-x));
}
__device__ __forceinline__ float tanh_fast(float x) {
    float e = __expf(-2.f * x);
    e = fminf(e, 1e30f);          // keep 1+e finite so rcp>0: tanh(-big) -> -1, not NaN
    return (1.f - e) * __builtin_amdgcn_rcpf(1.f + e);
}
__device__ __forceinline__ void split2(float x, unsigned short& hi, unsigned short& lo) {
    const unsigned u = __float_as_uint(x);
    hi = (unsigned short)(u >> 16);
    const float r = x - __uint_as_float(u & 0xFFFF0000u);  // exact
    lo = (unsigned short)(__float_as_uint(r) >> 16);
}

// ---------------- input MLP: 2 -> 16 relu -> 16 ----------------
__global__ __launch_bounds__(256)
void mlp_in_kernel(const float* __restrict__ x,
                   const float* __restrict__ w1, const float* __restrict__ b1,
                   const float* __restrict__ w2, const float* __restrict__ b2,
                   float* __restrict__ out) {
    const int gid = blockIdx.x * 256 + threadIdx.x;
    const float x0 = x[gid * 2 + 0];
    const float x1 = x[gid * 2 + 1];
    float hid[16];
#pragma unroll
    for (int j = 0; j < 16; ++j) {
        float v = fmaf(x1, w1[j * 2 + 1], fmaf(x0, w1[j * 2 + 0], b1[j]));
        hid[j] = fmaxf(0.f, v);
    }
    float o[16];
#pragma unroll
    for (int oo = 0; oo < 16; ++oo) {
        float acc = b2[oo];
#pragma unroll
        for (int j = 0; j < 16; ++j) acc = fmaf(hid[j], w2[oo * 16 + j], acc);
        o[oo] = acc;
    }
    float4* op = (float4*)(out + gid * 16);
#pragma unroll
    for (int q = 0; q < 4; ++q) {
        float4 v;
        v.x = o[q * 4 + 0]; v.y = o[q * 4 + 1]; v.z = o[q * 4 + 2]; v.w = o[q * 4 + 3];
        op[q] = v;
    }
}

// ---------------- fused LSTM layer pair, M=8, 512 threads ----------------
// IA/IPADA: layer A input width / padded width. Layer B always 64/64.
template <int IA, int IPADA>
__global__ __launch_bounds__(512, 2)
void lstm_pair(const float* __restrict__ xmlp,   // A input iff IA==16
               unsigned* __restrict__ P,          // packed h buffer (A in / B out)
               float* __restrict__ houtf,         // B out iff last
               const int last,
               const float* __restrict__ wihA, const float* __restrict__ whhA,
               const float* __restrict__ biA, const float* __restrict__ bhA,
               const float* __restrict__ wihB, const float* __restrict__ whhB,
               const float* __restrict__ biB, const float* __restrict__ bhB) {
    constexpr int KTA = (IPADA + 64) / 32;
    __shared__ unsigned short pAh[2][16 * LDP], pAl[2][16 * LDP];
    __shared__ unsigned short pBh[2][16 * LDP], pBl[2][16 * LDP];

    const int tid = threadIdx.x;
    const int wv = tid >> 6, lane = tid & 63, l16 = lane & 15, quad = lane >> 4;
    const int grp = wv >> 2;   // 0 = layer A, 1 = layer B
    const int wg = wv & 3;     // j-group within layer
    const int base = blockIdx.x * 8;

    for (int e = tid; e < 2 * 16 * LDP; e += 512) {
        (&pAh[0][0])[e] = 0; (&pAl[0][0])[e] = 0;
        (&pBh[0][0])[e] = 0; (&pBl[0][0])[e] = 0;
    }

    // per-wave layer params (wave-uniform)
    const int I    = grp ? 64 : IA;
    const int IPAD = grp ? 64 : IPADA;
    const int KT   = grp ? 4  : KTA;
    const float* wih = grp ? wihB : wihA;
    const float* whh = grp ? whhB : whhA;
    const float* bi  = grp ? biB  : biA;
    const float* bh  = grp ? bhB  : bhA;

    // --- weight B-fragments, gate-per-tile: tile gt = gate gt for j in [16wg,16wg+16) ---
    const int jg = 16 * wg + l16;
    bf16x8 bhi[4][4], blo[4][4];  // [kt][gt]
    float bsum[4];
#pragma unroll
    for (int gt = 0; gt < 4; ++gt) {
        const int n = gt * 64 + jg;
        bsum[gt] = bi[n] + bh[n];
#pragma unroll
        for (int kt = 0; kt < 4; ++kt) {
            bf16x8 vh = {0, 0, 0, 0, 0, 0, 0, 0};
            bf16x8 vl = {0, 0, 0, 0, 0, 0, 0, 0};
            if (kt < KT) {
#pragma unroll
                for (int j = 0; j < 8; ++j) {
                    const int k = kt * 32 + quad * 8 + j;
                    float w = 0.f;
                    if (k < I) w = wih[n * I + k];
                    else if (k >= IPAD) w = whh[n * 64 + (k - IPAD)];
                    unsigned short h_, l_;
                    split2(w, h_, l_);
                    vh[j] = (short)h_;
                    vl[j] = (short)l_;
                }
            }
            bhi[kt][gt] = vh;
            blo[kt][gt] = vl;
        }
    }

    // c-state: lane (quad<2) owns rows quad*4+rr (batch rows 0..7), col jg
    float cst[4] = {0.f, 0.f, 0.f, 0.f};

    // --- staging setup (A-group only): x(0) -> pA[0]; prefetch x(1) ---
    float xrf = 0.f;
    uint2 xru = {0u, 0u};
    int sr = 0, sc = 0;
    if (grp == 0) {
        if (IA == 16) {
            sr = tid >> 4; sc = tid & 15;
            if (tid < 128) {
                xrf = xmlp[((size_t)(base + sr) * TT + 0) * 16 + sc];
                unsigned short h_, l_;
                split2(xrf, h_, l_);
                pAh[0][sr * LDP + sc] = h_;
                pAl[0][sr * LDP + sc] = l_;
                xrf = xmlp[((size_t)(base + sr) * TT + 1) * 16 + sc];
            }
        } else {
            sr = tid >> 5; sc = (tid & 31) * 2;
            xru = *(const uint2*)&P[((size_t)(base + sr) * TT + 0) * 64 + sc];
            pAh[0][sr * LDP + sc + 0] = (unsigned short)(xru.x >> 16);
            pAl[0][sr * LDP + sc + 0] = (unsigned short)(xru.x & 0xffffu);
            pAh[0][sr * LDP + sc + 1] = (unsigned short)(xru.y >> 16);
            pAl[0][sr * LDP + sc + 1] = (unsigned short)(xru.y & 0xffffu);
            xru = *(const uint2*)&P[((size_t)(base + sr) * TT + 1) * 64 + sc];
        }
    }
    __syncthreads();

    for (int s = 0; s <= TT; ++s) {
        // ============ layer A: step t = s ============
        if (grp == 0 && s < TT) {
            const int t = s, pb = s & 1;
            f32x4 a0[4], a1[4], a2[4];
#pragma unroll
            for (int gt = 0; gt < 4; ++gt) {
                a0[gt][0] = bsum[gt]; a0[gt][1] = bsum[gt];
                a0[gt][2] = bsum[gt]; a0[gt][3] = bsum[gt];
                a1[gt] = (f32x4){0.f, 0.f, 0.f, 0.f};
                a2[gt] = (f32x4){0.f, 0.f, 0.f, 0.f};
            }
#pragma unroll
            for (int kt = 0; kt < 4; ++kt) {
                if (kt < KTA) {
                    const int aoff = l16 * LDP + kt * 32 + quad * 8;
                    const bf16x8 ahi = *(const bf16x8*)&pAh[pb][aoff];
                    const bf16x8 alo = *(const bf16x8*)&pAl[pb][aoff];
#pragma unroll
                    for (int gt = 0; gt < 4; ++gt) {
                        a0[gt] = __builtin_amdgcn_mfma_f32_16x16x32_bf16(ahi, bhi[kt][gt], a0[gt], 0, 0, 0);
                        a1[gt] = __builtin_amdgcn_mfma_f32_16x16x32_bf16(alo, bhi[kt][gt], a1[gt], 0, 0, 0);
                        a2[gt] = __builtin_amdgcn_mfma_f32_16x16x32_bf16(ahi, blo[kt][gt], a2[gt], 0, 0, 0);
                    }
                }
            }
            if (quad < 2) {
#pragma unroll
                for (int rr = 0; rr < 4; ++rr) {
                    const float gi = (a0[0][rr] + a1[0][rr]) + a2[0][rr];
                    const float gf = (a0[1][rr] + a1[1][rr]) + a2[1][rr];
                    const float gg = (a0[2][rr] + a1[2][rr]) + a2[2][rr];
                    const float go = (a0[3][rr] + a1[3][rr]) + a2[3][rr];
                    const float iv = sigmoid_fast(gi), fv = sigmoid_fast(gf);
                    const float gv = tanh_fast(gg), ov = sigmoid_fast(go);
                    const float cn = fv * cst[rr] + iv * gv;
                    cst[rr] = cn;
                    const float h = ov * tanh_fast(cn);
                    const int R = quad * 4 + rr;
                    unsigned short h_, l_;
                    split2(h, h_, l_);
                    pAh[pb ^ 1][R * LDP + IPADA + jg] = h_;   // own recurrence
                    pAl[pb ^ 1][R * LDP + IPADA + jg] = l_;
                    pBh[pb][R * LDP + jg] = h_;               // B's x-region
                    pBl[pb][R * LDP + jg] = l_;
                }
            }
            // stage x(t+1) into pA[pb^1]; prefetch x(t+2)
            if (IA == 16) {
                if (tid < 128) {
                    unsigned short h_, l_;
                    split2(xrf, h_, l_);
                    pAh[pb ^ 1][sr * LDP + sc] = h_;
                    pAl[pb ^ 1][sr * LDP + sc] = l_;
                    const int tp = (t + 2) & (TT - 1);
                    xrf = xmlp[((size_t)(base + sr) * TT + tp) * 16 + sc];
                }
            } else {
                pAh[pb ^ 1][sr * LDP + sc + 0] = (unsigned short)(xru.x >> 16);
                pAl[pb ^ 1][sr * LDP + sc + 0] = (unsigned short)(xru.x & 0xffffu);
                pAh[pb ^ 1][sr * LDP + sc + 1] = (unsigned short)(xru.y >> 16);
                pAl[pb ^ 1][sr * LDP + sc + 1] = (unsigned short)(xru.y & 0xffffu);
                const int tp = (t + 2) & (TT - 1);
                xru = *(const uint2*)&P[((size_t)(base + sr) * TT + tp) * 64 + sc];
            }
        }

        // ============ layer B: step t = s-1 ============
        if (grp == 1 && s >= 1) {
            const int t = s - 1, pb = t & 1;
            f32x4 a0[4], a1[4], a2[4];
#pragma unroll
            for (int gt = 0; gt < 4; ++gt) {
                a0[gt][0] = bsum[gt]; a0[gt][1] = bsum[gt];
                a0[gt][2] = bsum[gt]; a0[gt][3] = bsum[gt];
                a1[gt] = (f32x4){0.f, 0.f, 0.f, 0.f};
                a2[gt] = (f32x4){0.f, 0.f, 0.f, 0.f};
            }
#pragma unroll
            for (int kt = 0; kt < 4; ++kt) {
                const int aoff = l16 * LDP + kt * 32 + quad * 8;
                const bf16x8 ahi = *(const bf16x8*)&pBh[pb][aoff];
                const bf16x8 alo = *(const bf16x8*)&pBl[pb][aoff];
#pragma unroll
                for (int gt = 0; gt < 4; ++gt) {
                    a0[gt] = __builtin_amdgcn_mfma_f32_16x16x32_bf16(ahi, bhi[kt][gt], a0[gt], 0, 0, 0);
                    a1[gt] = __builtin_amdgcn_mfma_f32_16x16x32_bf16(alo, bhi[kt][gt], a1[gt], 0, 0, 0);
                    a2[gt] = __builtin_amdgcn_mfma_f32_16x16x32_bf16(ahi, blo[kt][gt], a2[gt], 0, 0, 0);
                }
            }
            if (quad < 2) {
#pragma unroll
                for (int rr = 0; rr < 4; ++rr) {
                    const float gi = (a0[0][rr] + a1[0][rr]) + a2[0][rr];
                    const float gf = (a0[1][rr] + a1[1][rr]) + a2[1][rr];
                    const float gg = (a0[2][rr] + a1[2][rr]) + a2[2][rr];
                    const float go = (a0[3][rr] + a1[3][rr]) + a2[3][rr];
                    const float iv = sigmoid_fast(gi), fv = sigmoid_fast(gf);
                    const float gv = tanh_fast(gg), ov = sigmoid_fast(go);
                    const float cn = fv * cst[rr] + iv * gv;
                    cst[rr] = cn;
                    const float h = ov * tanh_fast(cn);
                    const int R = quad * 4 + rr;
                    unsigned short h_, l_;
                    split2(h, h_, l_);
                    pBh[pb ^ 1][R * LDP + 64 + jg] = h_;   // own recurrence (cols 64-127)
                    pBl[pb ^ 1][R * LDP + 64 + jg] = l_;
                    if (!last) {
                        P[((size_t)(base + R) * TT + t) * 64 + jg] =
                            ((unsigned)h_ << 16) | (unsigned)l_;
                    } else {
                        houtf[((size_t)(base + R) * TT + t) * HH + jg] = h;
                    }
                }
            }
        }
        __syncthreads();
    }
}

// ---------------- output MLP: 64 -> 32 relu -> 4 ----------------
__global__ __launch_bounds__(256)
void mlp_out_kernel(const float* __restrict__ hin,
                    const float* __restrict__ wo1, const float* __restrict__ bo1,
                    const float* __restrict__ wo2, const float* __restrict__ bo2,
                    float* __restrict__ out) {
    __shared__ __align__(16) float wo1_s[32 * 64];
    __shared__ float bo1_s[32];
    __shared__ float wo2_s[4 * 32];
    __shared__ float bo2_s[4];
    const int tid = threadIdx.x;
    for (int e = tid; e < 32 * 64; e += 256) wo1_s[e] = wo1[e];
    if (tid < 32) bo1_s[tid] = bo1[tid];
    if (tid < 128) wo2_s[tid] = wo2[tid];
    if (tid < 4) bo2_s[tid] = bo2[tid];
    __syncthreads();

    const int gid = blockIdx.x * 256 + tid;
    const float4* hv = (const float4*)(hin + gid * 64);
    float4 h[16];
#pragma unroll
    for (int q = 0; q < 16; ++q) h[q] = hv[q];

    float m1[32];
#pragma unroll
    for (int o = 0; o < 32; ++o) {
        float acc = bo1_s[o];
        const float4* wrow = (const float4*)(wo1_s + o * 64);
#pragma unroll
        for (int q = 0; q < 16; ++q) {
            const float4 w = wrow[q];
            acc = fmaf(h[q].x, w.x, acc);
            acc = fmaf(h[q].y, w.y, acc);
            acc = fmaf(h[q].z, w.z, acc);
            acc = fmaf(h[q].w, w.w, acc);
        }
        m1[o] = fmaxf(0.f, acc);
    }
    float r[4];
#pragma unroll
    for (int q = 0; q < 4; ++q) {
        float acc = bo2_s[q];
#pragma unroll
        for (int o = 0; o < 32; ++o) acc = fmaf(m1[o], wo2_s[q * 32 + o], acc);
        r[q] = acc;
    }
    float4 res;
    res.x = r[0]; res.y = r[1]; res.z = r[2]; res.w = r[3];
    ((float4*)out)[gid] = res;
}

extern "C" void kernel_launch(void* const* d_in, const int* in_sizes, int n_in,
                              void* d_out, int out_size, void* d_ws, size_t ws_size,
                              hipStream_t stream) {
    const float* x     = (const float*)d_in[0];
    const float* w1    = (const float*)d_in[1];
    const float* b1    = (const float*)d_in[2];
    const float* w2    = (const float*)d_in[3];
    const float* b2    = (const float*)d_in[4];
    const float* w_ih0 = (const float*)d_in[5];
    const float* w_hh0 = (const float*)d_in[6];
    const float* b_ih0 = (const float*)d_in[7];
    const float* b_hh0 = (const float*)d_in[8];
    const float* w_ih  = (const float*)d_in[9];
    const float* w_hh  = (const float*)d_in[10];
    const float* b_ih  = (const float*)d_in[11];
    const float* b_hh  = (const float*)d_in[12];
    const float* wo1   = (const float*)d_in[13];
    const float* bo1   = (const float*)d_in[14];
    const float* wo2   = (const float*)d_in[15];
    const float* bo2   = (const float*)d_in[16];

    // workspace: buf_mlp B*T*16 f32 (8 MB) | P B*T*64 u32 packed (32 MB) | bufH B*T*64 f32 (32 MB)
    float* buf_mlp = (float*)d_ws;
    unsigned* P = (unsigned*)(buf_mlp + (size_t)BATCH * TT * 16);
    float* bufH = (float*)(P + (size_t)BATCH * TT * 64);

    const int nbt_blocks = (BATCH * TT) / 256;  // 512

    mlp_in_kernel<<<nbt_blocks, 256, 0, stream>>>(x, w1, b1, w2, b2, buf_mlp);

    // pair 0: layers 0,1
    lstm_pair<16, 32><<<BATCH / 8, 512, 0, stream>>>(
        buf_mlp, P, bufH, 0,
        w_ih0, w_hh0, b_ih0, b_hh0,
        w_ih + (size_t)0 * 256 * 64, w_hh + (size_t)0 * 256 * 64, b_ih + 0 * 256, b_hh + 0 * 256);

    // pairs 1..3: layers (2,3), (4,5), (6,7) -> w_ih/w_hh indices (1,2), (3,4), (5,6)
    for (int p = 1; p < 4; ++p) {
        const int la = 2 * p - 1, lb = 2 * p;  // indices into w_ih/w_hh arrays (layer l -> idx l-1)
        lstm_pair<64, 64><<<BATCH / 8, 512, 0, stream>>>(
            buf_mlp, P, bufH, (p == 3) ? 1 : 0,
            w_ih + (size_t)la * 256 * 64, w_hh + (size_t)la * 256 * 64,
            b_ih + la * 256, b_hh + la * 256,
            w_ih + (size_t)lb * 256 * 64, w_hh + (size_t)lb * 256 * 64,
            b_ih + lb * 256, b_hh + lb * 256);
    }

    mlp_out_kernel<<<nbt_blocks, 256, 0, stream>>>(bufH, wo1, bo1, wo2, bo2, (float*)d_out);
}

// Round 5
// 511.293 us; speedup vs baseline: 2.9392x; 1.1169x over previous
//
#include <hip/hip_runtime.h>

// x[2048,64,2] -> MLP(2->16 relu ->16) -> 8x LSTM(H=64) -> MLP(64->32 relu ->4)
// fp32 in/out. LSTM via split-bf16 MFMA (3-term, ~fp32 accuracy).
//
// Round 9 (resubmit; R4 bench never acquired a GPU): split-barrier layer pair
// + full-wave phase C.
//   4 dispatches, each fuses layers (2p, 2p+1). grid 256 x 512 threads, M=8.
//   Waves 0-3 (group A): layer A; waves 4-7 (group B): layer B, skewed ~1 step.
//   NO s_barrier in the step loop: two LDS wave-counters (cA, cB) with
//   workgroup-scope acquire/release. A@t waits {cA>=4t, cB>=4(t-1)};
//   B@t waits {cA>=4(t+1), cB>=4t}. Each SIMD holds one A-wave + one B-wave
//   at different phases -> MFMA pipe of one overlaps VALU of the other.
//   Phase C is FULL-WAVE: D-frag rows redistributed via ds_bpermute so each
//   lane handles 2 (row,j) cells (was: half-wave x 4 cells). h-writes 2-way
//   bank-free. Gate-per-tile weights (tile gt = gate gt) keep C register-local.
//   Panels double-buffered (parity); x register-prefetched 2 ahead.
//   Summation order of the 3 split terms identical to verified R1/R8.

#define BATCH 2048
#define TT 64
#define HH 64
#define LDP 136   // panel row stride in shorts

typedef short bf16x8 __attribute__((ext_vector_type(8)));
typedef float f32x4 __attribute__((ext_vector_type(4)));

__device__ __forceinline__ float sigmoid_fast(float x) {
    return __builtin_amdgcn_rcpf(1.f + __expf(-x));
}
__device__ __forceinline__ float tanh_fast(float x) {
    float e = __expf(-2.f * x);
    e = fminf(e, 1e30f);          // keep 1+e finite so rcp>0: tanh(-big) -> -1, not NaN
    return (1.f - e) * __builtin_amdgcn_rcpf(1.f + e);
}
__device__ __forceinline__ void split2(float x, unsigned short& hi, unsigned short& lo) {
    const unsigned u = __float_as_uint(x);
    hi = (unsigned short)(u >> 16);
    const float r = x - __uint_as_float(u & 0xFFFF0000u);  // exact
    lo = (unsigned short)(__float_as_uint(r) >> 16);
}
__device__ __forceinline__ void wg_wait(int* c, int v) {
    while (__hip_atomic_load(c, __ATOMIC_ACQUIRE, __HIP_MEMORY_SCOPE_WORKGROUP) < v)
        __builtin_amdgcn_s_sleep(1);
}
__device__ __forceinline__ void wg_bump(int* c, int lane) {
    if (lane == 0)
        __hip_atomic_fetch_add(c, 1, __ATOMIC_RELEASE, __HIP_MEMORY_SCOPE_WORKGROUP);
}

// ---------------- input MLP: 2 -> 16 relu -> 16 ----------------
__global__ __launch_bounds__(256)
void mlp_in_kernel(const float* __restrict__ x,
                   const float* __restrict__ w1, const float* __restrict__ b1,
                   const float* __restrict__ w2, const float* __restrict__ b2,
                   float* __restrict__ out) {
    const int gid = blockIdx.x * 256 + threadIdx.x;
    const float x0 = x[gid * 2 + 0];
    const float x1 = x[gid * 2 + 1];
    float hid[16];
#pragma unroll
    for (int j = 0; j < 16; ++j) {
        float v = fmaf(x1, w1[j * 2 + 1], fmaf(x0, w1[j * 2 + 0], b1[j]));
        hid[j] = fmaxf(0.f, v);
    }
    float o[16];
#pragma unroll
    for (int oo = 0; oo < 16; ++oo) {
        float acc = b2[oo];
#pragma unroll
        for (int j = 0; j < 16; ++j) acc = fmaf(hid[j], w2[oo * 16 + j], acc);
        o[oo] = acc;
    }
    float4* op = (float4*)(out + gid * 16);
#pragma unroll
    for (int q = 0; q < 4; ++q) {
        float4 v;
        v.x = o[q * 4 + 0]; v.y = o[q * 4 + 1]; v.z = o[q * 4 + 2]; v.w = o[q * 4 + 3];
        op[q] = v;
    }
}

// ---------------- fused LSTM layer pair, split-barrier, M=8, 512 threads ----------------
// IA/IPADA: layer A input width / padded width. Layer B always 64/64.
template <int IA, int IPADA>
__global__ __launch_bounds__(512, 2)
void lstm_pair(const float* __restrict__ xmlp,   // A input iff IA==16
               unsigned* __restrict__ P,          // packed h buffer (A in / B out)
               float* __restrict__ houtf,         // B out iff last
               const int last,
               const float* __restrict__ wihA, const float* __restrict__ whhA,
               const float* __restrict__ biA, const float* __restrict__ bhA,
               const float* __restrict__ wihB, const float* __restrict__ whhB,
               const float* __restrict__ biB, const float* __restrict__ bhB) {
    constexpr int KTA = (IPADA + 64) / 32;
    __shared__ unsigned short pAh[2][16 * LDP], pAl[2][16 * LDP];
    __shared__ unsigned short pBh[2][16 * LDP], pBl[2][16 * LDP];
    __shared__ int cA, cB;

    const int tid = threadIdx.x;
    const int wv = tid >> 6, lane = tid & 63, l16 = lane & 15, quad = lane >> 4;
    const int grp = wv >> 2;   // 0 = layer A, 1 = layer B
    const int wg = wv & 3;     // j-group within layer
    const int base = blockIdx.x * 8;
    const bool lo32 = (lane < 32);
    const int bpi = (lane & 31) << 2;   // ds_bpermute byte index: partner lane-32

    if (tid == 0) { cA = 0; cB = 0; }
    for (int e = tid; e < 2 * 16 * LDP; e += 512) {
        (&pAh[0][0])[e] = 0; (&pAl[0][0])[e] = 0;
        (&pBh[0][0])[e] = 0; (&pBl[0][0])[e] = 0;
    }

    // per-wave layer params (wave-uniform)
    const int I    = grp ? 64 : IA;
    const int IPAD = grp ? 64 : IPADA;
    const int KT   = grp ? 4  : KTA;
    const float* wih = grp ? wihB : wihA;
    const float* whh = grp ? whhB : whhA;
    const float* bi  = grp ? biB  : biA;
    const float* bh  = grp ? bhB  : bhA;

    // --- weight B-fragments, gate-per-tile: tile gt = gate gt for j in [16wg,16wg+16) ---
    const int jg = 16 * wg + l16;
    bf16x8 bhi[4][4], blo[4][4];  // [kt][gt]
    float bsum[4];
#pragma unroll
    for (int gt = 0; gt < 4; ++gt) {
        const int n = gt * 64 + jg;
        bsum[gt] = bi[n] + bh[n];
#pragma unroll
        for (int kt = 0; kt < 4; ++kt) {
            bf16x8 vh = {0, 0, 0, 0, 0, 0, 0, 0};
            bf16x8 vl = {0, 0, 0, 0, 0, 0, 0, 0};
            if (kt < KT) {
#pragma unroll
                for (int j = 0; j < 8; ++j) {
                    const int k = kt * 32 + quad * 8 + j;
                    float w = 0.f;
                    if (k < I) w = wih[n * I + k];
                    else if (k >= IPAD) w = whh[n * 64 + (k - IPAD)];
                    unsigned short h_, l_;
                    split2(w, h_, l_);
                    vh[j] = (short)h_;
                    vl[j] = (short)l_;
                }
            }
            bhi[kt][gt] = vh;
            blo[kt][gt] = vl;
        }
    }

    // c-state: 2 cells/lane, rows row0+r, col jg
    float cs[2] = {0.f, 0.f};
    const int row0 = (quad & 1) * 4 + ((quad >> 1) << 1);

    // --- staging setup (A-group only): x(0) -> pA[0]; prefetch x(1) ---
    float xrf = 0.f;
    uint2 xru = {0u, 0u};
    int sr = 0, sc = 0;
    if (grp == 0) {
        if (IA == 16) {
            sr = tid >> 4; sc = tid & 15;
            if (tid < 128) {
                xrf = xmlp[((size_t)(base + sr) * TT + 0) * 16 + sc];
                unsigned short h_, l_;
                split2(xrf, h_, l_);
                pAh[0][sr * LDP + sc] = h_;
                pAl[0][sr * LDP + sc] = l_;
                xrf = xmlp[((size_t)(base + sr) * TT + 1) * 16 + sc];
            }
        } else {
            sr = tid >> 5; sc = (tid & 31) * 2;
            xru = *(const uint2*)&P[((size_t)(base + sr) * TT + 0) * 64 + sc];
            pAh[0][sr * LDP + sc + 0] = (unsigned short)(xru.x >> 16);
            pAl[0][sr * LDP + sc + 0] = (unsigned short)(xru.x & 0xffffu);
            pAh[0][sr * LDP + sc + 1] = (unsigned short)(xru.y >> 16);
            pAl[0][sr * LDP + sc + 1] = (unsigned short)(xru.y & 0xffffu);
            xru = *(const uint2*)&P[((size_t)(base + sr) * TT + 1) * 64 + sc];
        }
    }
    __syncthreads();   // panels + counters ready; last barrier in the kernel

    if (grp == 0) {
        // ================= group A: layer A, steps 0..63 =================
        for (int t = 0; t < TT; ++t) {
            const int pb = t & 1;
            if (t) {
                wg_wait(&cA, 4 * t);
                if (t >= 2) wg_wait(&cB, 4 * (t - 1));
            }
            f32x4 a0[4], a1[4], a2[4];
#pragma unroll
            for (int gt = 0; gt < 4; ++gt) {
                a0[gt][0] = bsum[gt]; a0[gt][1] = bsum[gt];
                a0[gt][2] = bsum[gt]; a0[gt][3] = bsum[gt];
                a1[gt] = (f32x4){0.f, 0.f, 0.f, 0.f};
                a2[gt] = (f32x4){0.f, 0.f, 0.f, 0.f};
            }
#pragma unroll
            for (int kt = 0; kt < KTA; ++kt) {
                const int aoff = l16 * LDP + kt * 32 + quad * 8;
                const bf16x8 ahi = *(const bf16x8*)&pAh[pb][aoff];
                const bf16x8 alo = *(const bf16x8*)&pAl[pb][aoff];
#pragma unroll
                for (int gt = 0; gt < 4; ++gt) {
                    a0[gt] = __builtin_amdgcn_mfma_f32_16x16x32_bf16(ahi, bhi[kt][gt], a0[gt], 0, 0, 0);
                    a1[gt] = __builtin_amdgcn_mfma_f32_16x16x32_bf16(alo, bhi[kt][gt], a1[gt], 0, 0, 0);
                    a2[gt] = __builtin_amdgcn_mfma_f32_16x16x32_bf16(ahi, blo[kt][gt], a2[gt], 0, 0, 0);
                }
            }
            // sums (exact R8 order) + full-wave redistribution
            f32x4 s4[4];
#pragma unroll
            for (int gt = 0; gt < 4; ++gt) s4[gt] = (a0[gt] + a1[gt]) + a2[gt];
            float gk[4][2];
#pragma unroll
            for (int gt = 0; gt < 4; ++gt) {
#pragma unroll
                for (int r = 0; r < 2; ++r) {
                    const float up = __uint_as_float(
                        __builtin_amdgcn_ds_bpermute(bpi, __float_as_uint(s4[gt][r + 2])));
                    gk[gt][r] = lo32 ? s4[gt][r] : up;
                }
            }
#pragma unroll
            for (int r = 0; r < 2; ++r) {
                const float iv = sigmoid_fast(gk[0][r]);
                const float fv = sigmoid_fast(gk[1][r]);
                const float gv = tanh_fast(gk[2][r]);
                const float ov = sigmoid_fast(gk[3][r]);
                const float cn = fv * cs[r] + iv * gv;
                cs[r] = cn;
                const float h = ov * tanh_fast(cn);
                const int R = row0 + r;
                unsigned short h_, l_;
                split2(h, h_, l_);
                pAh[pb ^ 1][R * LDP + IPADA + jg] = h_;   // own recurrence
                pAl[pb ^ 1][R * LDP + IPADA + jg] = l_;
                pBh[pb][R * LDP + jg] = h_;               // B's x-region, step t
                pBl[pb][R * LDP + jg] = l_;
            }
            // stage x(t+1) into pA[pb^1]; prefetch x(t+2)
            if (IA == 16) {
                if (tid < 128) {
                    unsigned short h_, l_;
                    split2(xrf, h_, l_);
                    pAh[pb ^ 1][sr * LDP + sc] = h_;
                    pAl[pb ^ 1][sr * LDP + sc] = l_;
                    const int tp = (t + 2) & (TT - 1);
                    xrf = xmlp[((size_t)(base + sr) * TT + tp) * 16 + sc];
                }
            } else {
                pAh[pb ^ 1][sr * LDP + sc + 0] = (unsigned short)(xru.x >> 16);
                pAl[pb ^ 1][sr * LDP + sc + 0] = (unsigned short)(xru.x & 0xffffu);
                pAh[pb ^ 1][sr * LDP + sc + 1] = (unsigned short)(xru.y >> 16);
                pAl[pb ^ 1][sr * LDP + sc + 1] = (unsigned short)(xru.y & 0xffffu);
                const int tp = (t + 2) & (TT - 1);
                xru = *(const uint2*)&P[((size_t)(base + sr) * TT + tp) * 64 + sc];
            }
            wg_bump(&cA, lane);
        }
    } else {
        // ================= group B: layer B, steps 0..63 =================
        for (int t = 0; t < TT; ++t) {
            const int pb = t & 1;
            wg_wait(&cA, 4 * (t + 1));
            if (t) wg_wait(&cB, 4 * t);
            f32x4 a0[4], a1[4], a2[4];
#pragma unroll
            for (int gt = 0; gt < 4; ++gt) {
                a0[gt][0] = bsum[gt]; a0[gt][1] = bsum[gt];
                a0[gt][2] = bsum[gt]; a0[gt][3] = bsum[gt];
                a1[gt] = (f32x4){0.f, 0.f, 0.f, 0.f};
                a2[gt] = (f32x4){0.f, 0.f, 0.f, 0.f};
            }
#pragma unroll
            for (int kt = 0; kt < 4; ++kt) {
                const int aoff = l16 * LDP + kt * 32 + quad * 8;
                const bf16x8 ahi = *(const bf16x8*)&pBh[pb][aoff];
                const bf16x8 alo = *(const bf16x8*)&pBl[pb][aoff];
#pragma unroll
                for (int gt = 0; gt < 4; ++gt) {
                    a0[gt] = __builtin_amdgcn_mfma_f32_16x16x32_bf16(ahi, bhi[kt][gt], a0[gt], 0, 0, 0);
                    a1[gt] = __builtin_amdgcn_mfma_f32_16x16x32_bf16(alo, bhi[kt][gt], a1[gt], 0, 0, 0);
                    a2[gt] = __builtin_amdgcn_mfma_f32_16x16x32_bf16(ahi, blo[kt][gt], a2[gt], 0, 0, 0);
                }
            }
            f32x4 s4[4];
#pragma unroll
            for (int gt = 0; gt < 4; ++gt) s4[gt] = (a0[gt] + a1[gt]) + a2[gt];
            float gk[4][2];
#pragma unroll
            for (int gt = 0; gt < 4; ++gt) {
#pragma unroll
                for (int r = 0; r < 2; ++r) {
                    const float up = __uint_as_float(
                        __builtin_amdgcn_ds_bpermute(bpi, __float_as_uint(s4[gt][r + 2])));
                    gk[gt][r] = lo32 ? s4[gt][r] : up;
                }
            }
#pragma unroll
            for (int r = 0; r < 2; ++r) {
                const float iv = sigmoid_fast(gk[0][r]);
                const float fv = sigmoid_fast(gk[1][r]);
                const float gv = tanh_fast(gk[2][r]);
                const float ov = sigmoid_fast(gk[3][r]);
                const float cn = fv * cs[r] + iv * gv;
                cs[r] = cn;
                const float h = ov * tanh_fast(cn);
                const int R = row0 + r;
                unsigned short h_, l_;
                split2(h, h_, l_);
                pBh[pb ^ 1][R * LDP + 64 + jg] = h_;   // own recurrence (cols 64-127)
                pBl[pb ^ 1][R * LDP + 64 + jg] = l_;
                if (!last) {
                    P[((size_t)(base + R) * TT + t) * 64 + jg] =
                        ((unsigned)h_ << 16) | (unsigned)l_;
                } else {
                    houtf[((size_t)(base + R) * TT + t) * HH + jg] = h;
                }
            }
            wg_bump(&cB, lane);
        }
    }
}

// ---------------- output MLP: 64 -> 32 relu -> 4 ----------------
__global__ __launch_bounds__(256)
void mlp_out_kernel(const float* __restrict__ hin,
                    const float* __restrict__ wo1, const float* __restrict__ bo1,
                    const float* __restrict__ wo2, const float* __restrict__ bo2,
                    float* __restrict__ out) {
    __shared__ __align__(16) float wo1_s[32 * 64];
    __shared__ float bo1_s[32];
    __shared__ float wo2_s[4 * 32];
    __shared__ float bo2_s[4];
    const int tid = threadIdx.x;
    for (int e = tid; e < 32 * 64; e += 256) wo1_s[e] = wo1[e];
    if (tid < 32) bo1_s[tid] = bo1[tid];
    if (tid < 128) wo2_s[tid] = wo2[tid];
    if (tid < 4) bo2_s[tid] = bo2[tid];
    __syncthreads();

    const int gid = blockIdx.x * 256 + tid;
    const float4* hv = (const float4*)(hin + gid * 64);
    float4 h[16];
#pragma unroll
    for (int q = 0; q < 16; ++q) h[q] = hv[q];

    float m1[32];
#pragma unroll
    for (int o = 0; o < 32; ++o) {
        float acc = bo1_s[o];
        const float4* wrow = (const float4*)(wo1_s + o * 64);
#pragma unroll
        for (int q = 0; q < 16; ++q) {
            const float4 w = wrow[q];
            acc = fmaf(h[q].x, w.x, acc);
            acc = fmaf(h[q].y, w.y, acc);
            acc = fmaf(h[q].z, w.z, acc);
            acc = fmaf(h[q].w, w.w, acc);
        }
        m1[o] = fmaxf(0.f, acc);
    }
    float r[4];
#pragma unroll
    for (int q = 0; q < 4; ++q) {
        float acc = bo2_s[q];
#pragma unroll
        for (int o = 0; o < 32; ++o) acc = fmaf(m1[o], wo2_s[q * 32 + o], acc);
        r[q] = acc;
    }
    float4 res;
    res.x = r[0]; res.y = r[1]; res.z = r[2]; res.w = r[3];
    ((float4*)out)[gid] = res;
}

extern "C" void kernel_launch(void* const* d_in, const int* in_sizes, int n_in,
                              void* d_out, int out_size, void* d_ws, size_t ws_size,
                              hipStream_t stream) {
    const float* x     = (const float*)d_in[0];
    const float* w1    = (const float*)d_in[1];
    const float* b1    = (const float*)d_in[2];
    const float* w2    = (const float*)d_in[3];
    const float* b2    = (const float*)d_in[4];
    const float* w_ih0 = (const float*)d_in[5];
    const float* w_hh0 = (const float*)d_in[6];
    const float* b_ih0 = (const float*)d_in[7];
    const float* b_hh0 = (const float*)d_in[8];
    const float* w_ih  = (const float*)d_in[9];
    const float* w_hh  = (const float*)d_in[10];
    const float* b_ih  = (const float*)d_in[11];
    const float* b_hh  = (const float*)d_in[12];
    const float* wo1   = (const float*)d_in[13];
    const float* bo1   = (const float*)d_in[14];
    const float* wo2   = (const float*)d_in[15];
    const float* bo2   = (const float*)d_in[16];

    // workspace: buf_mlp B*T*16 f32 (8 MB) | P B*T*64 u32 packed (32 MB) | bufH B*T*64 f32 (32 MB)
    float* buf_mlp = (float*)d_ws;
    unsigned* P = (unsigned*)(buf_mlp + (size_t)BATCH * TT * 16);
    float* bufH = (float*)(P + (size_t)BATCH * TT * 64);

    const int nbt_blocks = (BATCH * TT) / 256;  // 512

    mlp_in_kernel<<<nbt_blocks, 256, 0, stream>>>(x, w1, b1, w2, b2, buf_mlp);

    // pair 0: layers 0,1
    lstm_pair<16, 32><<<BATCH / 8, 512, 0, stream>>>(
        buf_mlp, P, bufH, 0,
        w_ih0, w_hh0, b_ih0, b_hh0,
        w_ih + (size_t)0 * 256 * 64, w_hh + (size_t)0 * 256 * 64, b_ih + 0 * 256, b_hh + 0 * 256);

    // pairs 1..3: layers (2,3), (4,5), (6,7) -> w_ih/w_hh indices (1,2), (3,4), (5,6)
    for (int p = 1; p < 4; ++p) {
        const int la = 2 * p - 1, lb = 2 * p;  // indices into w_ih/w_hh arrays (layer l -> idx l-1)
        lstm_pair<64, 64><<<BATCH / 8, 512, 0, stream>>>(
            buf_mlp, P, bufH, (p == 3) ? 1 : 0,
            w_ih + (size_t)la * 256 * 64, w_hh + (size_t)la * 256 * 64,
            b_ih + la * 256, b_hh + la * 256,
            w_ih + (size_t)lb * 256 * 64, w_hh + (size_t)lb * 256 * 64,
            b_ih + lb * 256, b_hh + lb * 256);
    }

    mlp_out_kernel<<<nbt_blocks, 256, 0, stream>>>(bufH, wo1, bo1, wo2, bo2, (float*)d_out);
}